// Round 7
// baseline (136.794 us; speedup 1.0000x reference)
//
#include <hip/hip_runtime.h>

#define T_STEPS 128
#define RPB     32      // rows per block (4 waves x 8 rows); LDS tile 128x33 floats

// ---------------------------------------------------------------------------
// Fused prep: low gids build uint4 spike masks mask[c] (bit t2 of word q =
// spike at t = q*32+t2, 16B contiguous per column); high gids build per-row
// CSR starts for both sparse inputs via binary search on the sorted rows.
// ---------------------------------------------------------------------------
__global__ __launch_bounds__(256) void prep_kernel(
    const float* __restrict__ lgn_spikes, int lgn_C, uint4* __restrict__ lgn_mask,
    const float* __restrict__ bkg_spikes, int bkg_C, uint4* __restrict__ bkg_mask,
    const int* __restrict__ lgn_rows, int nnz_l, int* __restrict__ lgn_start,
    const int* __restrict__ bkg_rows, int nnz_b, int* __restrict__ bkg_start,
    int R)
{
    int gid = blockIdx.x * 256 + threadIdx.x;
    int totC = lgn_C + bkg_C;

    if (gid < totC) {
        const float* sp; uint4* mask; int C, cc;
        if (gid < lgn_C) { sp = lgn_spikes; mask = lgn_mask; C = lgn_C; cc = gid; }
        else             { sp = bkg_spikes; mask = bkg_mask; C = bkg_C; cc = gid - lgn_C; }
        unsigned int m0 = 0u, m1 = 0u, m2 = 0u, m3 = 0u;
        #pragma unroll 4
        for (int t = 0; t < 32; ++t) {
            if (sp[(size_t)(t)       * C + cc] != 0.0f) m0 |= (1u << t);
            if (sp[(size_t)(t +  32) * C + cc] != 0.0f) m1 |= (1u << t);
            if (sp[(size_t)(t +  64) * C + cc] != 0.0f) m2 |= (1u << t);
            if (sp[(size_t)(t +  96) * C + cc] != 0.0f) m3 |= (1u << t);
        }
        mask[cc] = make_uint4(m0, m1, m2, m3);
        return;
    }
    int r = gid - totC;
    if (r <= R) {
        {
            int lo = 0, hi = nnz_l;
            while (lo < hi) { int mid = (lo + hi) >> 1; if (lgn_rows[mid] < r) lo = mid + 1; else hi = mid; }
            lgn_start[r] = lo;
        }
        {
            int lo = 0, hi = nnz_b;
            while (lo < hi) { int mid = (lo + hi) >> 1; if (bkg_rows[mid] < r) lo = mid + 1; else hi = mid; }
            bkg_start[r] = lo;
        }
    }
}

// ---------------------------------------------------------------------------
// Main: WAVE = ONE ROW, LANES = TIMESTEPS (t=lane and t=lane+64).
//  - zero lane imbalance: wave runtime ~ its own row's nnz (mean ~7), no
//    max-of-64 inflation; variance averages over 200K independent waves.
//  - per-synapse data (col, w, uint4 mask) is wave-uniform -> scalar loads
//    on the SALU/K$ pipe; VALU per synapse = 2 cndmask + 2x(shift,and,neg,
//    add) covering ALL 128 timesteps.
//  - stores staged through a 128x32 LDS tile (row-dim stride 33: write is
//    2-way-bank-free, read conflict-free), then one coalesced store phase
//    (128B contiguous per chunk). Output written exactly once.
//  - LDS 16.9KB + low VGPR (launch_bounds min 8 waves/EU) -> 8 blocks/CU
//    = 32 waves/CU to hide the chained col->mask scalar-load latency.
// ---------------------------------------------------------------------------
__global__ __launch_bounds__(256, 8) void wave_row_kernel(
    const int* __restrict__ lgn_cols, const float* __restrict__ lgn_w,
    const int* __restrict__ lgn_start,
    const int* __restrict__ bkg_cols, const float* __restrict__ bkg_w,
    const int* __restrict__ bkg_start,
    const uint4* __restrict__ lgn_mask, const uint4* __restrict__ bkg_mask,
    int R, float* __restrict__ out)
{
    __shared__ float tile[T_STEPS * 33];   // [t][row], row extent padded to 33

    const int tid  = threadIdx.x;
    const int lane = tid & 63;
    const int wid  = tid >> 6;             // wave 0..3
    const int r0   = blockIdx.x * RPB;
    const unsigned int sh = lane & 31;
    const bool lo32 = lane < 32;

    #pragma unroll 1
    for (int k = 0; k < RPB / 4; ++k) {    // 8 rows per wave, sequential
        const int rl = wid * (RPB / 4) + k;
        const int r  = r0 + rl;
        float acc_lo = 0.0f, acc_hi = 0.0f;
        if (r < R) {
            {
                int i0 = lgn_start[r], i1 = lgn_start[r + 1];
                for (int i = i0; i < i1; ++i) {
                    int wb  = __float_as_int(lgn_w[i]);
                    uint4 m = lgn_mask[lgn_cols[i]];
                    unsigned int wlo = lo32 ? m.x : m.y;
                    unsigned int whi = lo32 ? m.z : m.w;
                    acc_lo += __int_as_float((-(int)((wlo >> sh) & 1u)) & wb);
                    acc_hi += __int_as_float((-(int)((whi >> sh) & 1u)) & wb);
                }
            }
            {
                int i0 = bkg_start[r], i1 = bkg_start[r + 1];
                for (int i = i0; i < i1; ++i) {
                    int wb  = __float_as_int(bkg_w[i]);
                    uint4 m = bkg_mask[bkg_cols[i]];
                    unsigned int wlo = lo32 ? m.x : m.y;
                    unsigned int whi = lo32 ? m.z : m.w;
                    acc_lo += __int_as_float((-(int)((wlo >> sh) & 1u)) & wb);
                    acc_hi += __int_as_float((-(int)((whi >> sh) & 1u)) & wb);
                }
            }
        }
        tile[lane * 33 + rl]        = acc_lo;   // banks (lane+rl)&31: 2-way, free
        tile[(lane + 64) * 33 + rl] = acc_hi;
    }
    __syncthreads();

    // store phase: lanes 0..31 of each 32-group cover 32 consecutive rows at
    // fixed t -> 128B contiguous per chunk; each element written exactly once
    const int rl2 = tid & 31;
    const int tg  = tid >> 5;               // 0..7
    const int rr  = r0 + rl2;
    if (rr < R) {
        #pragma unroll
        for (int k2 = 0; k2 < 16; ++k2) {
            int t = tg * 16 + k2;
            out[(size_t)t * R + rr] = tile[t * 33 + rl2];
        }
    }
}

// ---------------------------------------------------------------------------
// Fallback (small ws): inline binary search + direct float gathers.
// ---------------------------------------------------------------------------
__global__ __launch_bounds__(256) void sparse_fallback_kernel(
    const int* __restrict__ lgn_rows, const int* __restrict__ lgn_cols,
    const float* __restrict__ lgn_w, int nnz_l,
    const int* __restrict__ bkg_rows, const int* __restrict__ bkg_cols,
    const float* __restrict__ bkg_w, int nnz_b,
    const float* __restrict__ lgn_spikes, const float* __restrict__ bkg_spikes,
    int lgn_C, int bkg_C, int R,
    float* __restrict__ out)
{
    int r = blockIdx.x * 256 + threadIdx.x;
    int q = blockIdx.y;
    if (r >= R) return;

    float acc[32];
    #pragma unroll
    for (int t = 0; t < 32; ++t) acc[t] = 0.0f;

    {
        int lo = 0, hi = nnz_l;
        while (lo < hi) { int mid = (lo + hi) >> 1; if (lgn_rows[mid] < r) lo = mid + 1; else hi = mid; }
        for (int i = lo; i < nnz_l && lgn_rows[i] == r; ++i) {
            float wt = lgn_w[i];
            const float* sp = lgn_spikes + (size_t)(q * 32) * lgn_C + lgn_cols[i];
            #pragma unroll
            for (int t = 0; t < 32; ++t)
                acc[t] = fmaf(wt, sp[(size_t)t * lgn_C], acc[t]);
        }
    }
    {
        int lo = 0, hi = nnz_b;
        while (lo < hi) { int mid = (lo + hi) >> 1; if (bkg_rows[mid] < r) lo = mid + 1; else hi = mid; }
        for (int i = lo; i < nnz_b && bkg_rows[i] == r; ++i) {
            float wt = bkg_w[i];
            const float* sp = bkg_spikes + (size_t)(q * 32) * bkg_C + bkg_cols[i];
            #pragma unroll
            for (int t = 0; t < 32; ++t)
                acc[t] = fmaf(wt, sp[(size_t)t * bkg_C], acc[t]);
        }
    }

    float* op = out + (size_t)(q * 32) * R + r;
    #pragma unroll
    for (int t = 0; t < 32; ++t) op[(size_t)t * R] = acc[t];
}

extern "C" void kernel_launch(void* const* d_in, const int* in_sizes, int n_in,
                              void* d_out, int out_size, void* d_ws, size_t ws_size,
                              hipStream_t stream)
{
    const float* lgn_spikes = (const float*)d_in[0];
    const float* bkg_spikes = (const float*)d_in[1];
    const int*   lgn_rows   = (const int*)d_in[2];
    const int*   lgn_cols   = (const int*)d_in[3];
    const float* lgn_w      = (const float*)d_in[4];
    const int*   bkg_rows   = (const int*)d_in[5];
    const int*   bkg_cols   = (const int*)d_in[6];
    const float* bkg_w      = (const float*)d_in[7];
    float* out = (float*)d_out;

    const int nnz_l = in_sizes[2];
    const int nnz_b = in_sizes[5];
    const int lgn_C = in_sizes[0] / T_STEPS;   // 17400
    const int bkg_C = in_sizes[1] / T_STEPS;   // 100
    const int R     = out_size / T_STEPS;      // 200000

    // ws layout (16B-aligned sections)
    size_t off = 0;
    auto take = [&](size_t bytes) { size_t o = off; off = (off + bytes + 15) & ~(size_t)15; return o; };
    size_t o_lgn_start = take((size_t)(R + 1) * sizeof(int));
    size_t o_bkg_start = take((size_t)(R + 1) * sizeof(int));
    size_t o_lgn_mask  = take((size_t)lgn_C * sizeof(uint4));
    size_t o_bkg_mask  = take((size_t)bkg_C * sizeof(uint4));
    size_t need = off;

    dim3 blk(256);

    if (ws_size >= need) {
        char* ws = (char*)d_ws;
        int* lgn_start = (int*)(ws + o_lgn_start);
        int* bkg_start = (int*)(ws + o_bkg_start);
        uint4* lgn_mask = (uint4*)(ws + o_lgn_mask);
        uint4* bkg_mask = (uint4*)(ws + o_bkg_mask);

        int prep_threads = (lgn_C + bkg_C) + (R + 1);
        prep_kernel<<<(prep_threads + 255) / 256, blk, 0, stream>>>(
            lgn_spikes, lgn_C, lgn_mask, bkg_spikes, bkg_C, bkg_mask,
            lgn_rows, nnz_l, lgn_start, bkg_rows, nnz_b, bkg_start, R);

        const int NB = (R + RPB - 1) / RPB;     // 6250 blocks
        wave_row_kernel<<<NB, blk, 0, stream>>>(
            lgn_cols, lgn_w, lgn_start,
            bkg_cols, bkg_w, bkg_start,
            lgn_mask, bkg_mask, R, out);
    } else {
        dim3 grid_main((R + 255) / 256, 4);
        sparse_fallback_kernel<<<grid_main, blk, 0, stream>>>(
            lgn_rows, lgn_cols, lgn_w, nnz_l,
            bkg_rows, bkg_cols, bkg_w, nnz_b,
            lgn_spikes, bkg_spikes,
            lgn_C, bkg_C, R, out);
    }
}

// Round 8
// 66.549 us; speedup vs baseline: 2.0555x; 2.0555x over previous
//
#include <hip/hip_runtime.h>

#define T_STEPS 128

// ---------------------------------------------------------------------------
// Fused prep: low gids build spike bit-masks in PLANE layout mask[q*C + c]
// (bit t2 of plane q = spike at t = q*32 + t2); high gids build per-row CSR
// starts for both sparse inputs via binary search on the sorted rows.
// ---------------------------------------------------------------------------
__global__ __launch_bounds__(256) void prep_kernel(
    const float* __restrict__ lgn_spikes, int lgn_C, unsigned int* __restrict__ lgn_mask,
    const float* __restrict__ bkg_spikes, int bkg_C, unsigned int* __restrict__ bkg_mask,
    const int* __restrict__ lgn_rows, int nnz_l, int* __restrict__ lgn_start,
    const int* __restrict__ bkg_rows, int nnz_b, int* __restrict__ bkg_start,
    int R)
{
    int gid = blockIdx.x * 256 + threadIdx.x;
    int totC = lgn_C + bkg_C;

    if (gid < totC) {
        const float* sp; unsigned int* mask; int C, cc;
        if (gid < lgn_C) { sp = lgn_spikes; mask = lgn_mask; C = lgn_C; cc = gid; }
        else             { sp = bkg_spikes; mask = bkg_mask; C = bkg_C; cc = gid - lgn_C; }
        unsigned int m0 = 0u, m1 = 0u, m2 = 0u, m3 = 0u;
        #pragma unroll 4
        for (int t = 0; t < 32; ++t) {
            if (sp[(size_t)(t)       * C + cc] != 0.0f) m0 |= (1u << t);
            if (sp[(size_t)(t +  32) * C + cc] != 0.0f) m1 |= (1u << t);
            if (sp[(size_t)(t +  64) * C + cc] != 0.0f) m2 |= (1u << t);
            if (sp[(size_t)(t +  96) * C + cc] != 0.0f) m3 |= (1u << t);
        }
        mask[(size_t)0 * C + cc] = m0;
        mask[(size_t)1 * C + cc] = m1;
        mask[(size_t)2 * C + cc] = m2;
        mask[(size_t)3 * C + cc] = m3;
        return;
    }
    int r = gid - totC;
    if (r <= R) {
        {
            int lo = 0, hi = nnz_l;
            while (lo < hi) { int mid = (lo + hi) >> 1; if (lgn_rows[mid] < r) lo = mid + 1; else hi = mid; }
            lgn_start[r] = lo;
        }
        {
            int lo = 0, hi = nnz_b;
            while (lo < hi) { int mid = (lo + hi) >> 1; if (bkg_rows[mid] < r) lo = mid + 1; else hi = mid; }
            bkg_start[r] = lo;
        }
    }
}

// ---------------------------------------------------------------------------
// Main (round-1 skeleton + nibble-LUT): thread = (row r, t-quarter q),
// acc = float[32] in VGPRs. Per synapse: 1 col load + 1 w load + 1 mask
// word gather, then 8 nibbles -> ds_read_b128 of a 16-entry 0/1-float4 LUT
// + 4 v_fmac_f32 each (bit-exact: sel in {0.0,1.0}). ~1.8 VALU/(syn,t) vs
// ~4 for the shift/and/add select. 1-deep prefetch hides the col->mask
// load chain. Coalesced 256B/wave-instr stores, output written once.
// ---------------------------------------------------------------------------
__global__ __launch_bounds__(256, 6) void sparse_lut_kernel(
    const int* __restrict__ lgn_cols, const float* __restrict__ lgn_w,
    const int* __restrict__ lgn_start,
    const int* __restrict__ bkg_cols, const float* __restrict__ bkg_w,
    const int* __restrict__ bkg_start,
    const unsigned int* __restrict__ lgn_mask,  // [4][lgn_C]
    const unsigned int* __restrict__ bkg_mask,  // [4][bkg_C]
    int lgn_C, int bkg_C, int R,
    float* __restrict__ out)
{
    __shared__ float4 lut[16];
    const int tid = threadIdx.x;
    if (tid < 16)
        lut[tid] = make_float4((float)(tid & 1), (float)((tid >> 1) & 1),
                               (float)((tid >> 2) & 1), (float)((tid >> 3) & 1));
    __syncthreads();

    const int r = blockIdx.x * 256 + tid;
    const int q = blockIdx.y;
    if (r >= R) return;

    float acc[32];
    #pragma unroll
    for (int t = 0; t < 32; ++t) acc[t] = 0.0f;

    const unsigned int* lm = lgn_mask + (size_t)q * lgn_C;
    const unsigned int* bm = bkg_mask + (size_t)q * bkg_C;

    // expand mask word m via LUT, acc[t] += w * sel[t]
    #define ACC_MASK(m, wv)                                                  \
        _Pragma("unroll")                                                    \
        for (int nb = 0; nb < 8; ++nb) {                                     \
            float4 s = lut[(m >> (nb * 4)) & 15u];                           \
            acc[nb * 4 + 0] = fmaf(wv, s.x, acc[nb * 4 + 0]);                \
            acc[nb * 4 + 1] = fmaf(wv, s.y, acc[nb * 4 + 1]);                \
            acc[nb * 4 + 2] = fmaf(wv, s.z, acc[nb * 4 + 2]);                \
            acc[nb * 4 + 3] = fmaf(wv, s.w, acc[nb * 4 + 3]);                \
        }

    #define ACC_RANGE(cols_a, w_a, mask_p, i_lo, i_hi)                       \
    {                                                                        \
        int i0 = (i_lo), i1 = (i_hi);                                        \
        if (i0 < i1) {                                                       \
            float wv = w_a[i0];                                              \
            unsigned int m = mask_p[cols_a[i0]];                             \
            for (int i = i0; i < i1; ++i) {                                  \
                int ni = i + 1;                                              \
                float nwv = 0.0f; unsigned int nm = 0u;                      \
                if (ni < i1) { nwv = w_a[ni]; nm = mask_p[cols_a[ni]]; }     \
                ACC_MASK(m, wv)                                              \
                wv = nwv; m = nm;                                            \
            }                                                                \
        }                                                                    \
    }

    ACC_RANGE(lgn_cols, lgn_w, lm, lgn_start[r], lgn_start[r + 1])
    ACC_RANGE(bkg_cols, bkg_w, bm, bkg_start[r], bkg_start[r + 1])
    #undef ACC_RANGE
    #undef ACC_MASK

    float* op = out + (size_t)(q * 32) * R + r;
    #pragma unroll
    for (int t = 0; t < 32; ++t) op[(size_t)t * R] = acc[t];
}

// ---------------------------------------------------------------------------
// Fallback (small ws): inline binary search + direct float gathers.
// ---------------------------------------------------------------------------
__global__ __launch_bounds__(256) void sparse_fallback_kernel(
    const int* __restrict__ lgn_rows, const int* __restrict__ lgn_cols,
    const float* __restrict__ lgn_w, int nnz_l,
    const int* __restrict__ bkg_rows, const int* __restrict__ bkg_cols,
    const float* __restrict__ bkg_w, int nnz_b,
    const float* __restrict__ lgn_spikes, const float* __restrict__ bkg_spikes,
    int lgn_C, int bkg_C, int R,
    float* __restrict__ out)
{
    int r = blockIdx.x * 256 + threadIdx.x;
    int q = blockIdx.y;
    if (r >= R) return;

    float acc[32];
    #pragma unroll
    for (int t = 0; t < 32; ++t) acc[t] = 0.0f;

    {
        int lo = 0, hi = nnz_l;
        while (lo < hi) { int mid = (lo + hi) >> 1; if (lgn_rows[mid] < r) lo = mid + 1; else hi = mid; }
        for (int i = lo; i < nnz_l && lgn_rows[i] == r; ++i) {
            float wt = lgn_w[i];
            const float* sp = lgn_spikes + (size_t)(q * 32) * lgn_C + lgn_cols[i];
            #pragma unroll
            for (int t = 0; t < 32; ++t)
                acc[t] = fmaf(wt, sp[(size_t)t * lgn_C], acc[t]);
        }
    }
    {
        int lo = 0, hi = nnz_b;
        while (lo < hi) { int mid = (lo + hi) >> 1; if (bkg_rows[mid] < r) lo = mid + 1; else hi = mid; }
        for (int i = lo; i < nnz_b && bkg_rows[i] == r; ++i) {
            float wt = bkg_w[i];
            const float* sp = bkg_spikes + (size_t)(q * 32) * bkg_C + bkg_cols[i];
            #pragma unroll
            for (int t = 0; t < 32; ++t)
                acc[t] = fmaf(wt, sp[(size_t)t * bkg_C], acc[t]);
        }
    }

    float* op = out + (size_t)(q * 32) * R + r;
    #pragma unroll
    for (int t = 0; t < 32; ++t) op[(size_t)t * R] = acc[t];
}

extern "C" void kernel_launch(void* const* d_in, const int* in_sizes, int n_in,
                              void* d_out, int out_size, void* d_ws, size_t ws_size,
                              hipStream_t stream)
{
    const float* lgn_spikes = (const float*)d_in[0];
    const float* bkg_spikes = (const float*)d_in[1];
    const int*   lgn_rows   = (const int*)d_in[2];
    const int*   lgn_cols   = (const int*)d_in[3];
    const float* lgn_w      = (const float*)d_in[4];
    const int*   bkg_rows   = (const int*)d_in[5];
    const int*   bkg_cols   = (const int*)d_in[6];
    const float* bkg_w      = (const float*)d_in[7];
    float* out = (float*)d_out;

    const int nnz_l = in_sizes[2];
    const int nnz_b = in_sizes[5];
    const int lgn_C = in_sizes[0] / T_STEPS;   // 17400
    const int bkg_C = in_sizes[1] / T_STEPS;   // 100
    const int R     = out_size / T_STEPS;      // 200000

    // ws layout (16B-aligned sections)
    size_t off = 0;
    auto take = [&](size_t bytes) { size_t o = off; off = (off + bytes + 15) & ~(size_t)15; return o; };
    size_t o_lgn_start = take((size_t)(R + 1) * sizeof(int));
    size_t o_bkg_start = take((size_t)(R + 1) * sizeof(int));
    size_t o_lgn_mask  = take((size_t)4 * lgn_C * sizeof(unsigned int));
    size_t o_bkg_mask  = take((size_t)4 * bkg_C * sizeof(unsigned int));
    size_t need = off;

    dim3 blk(256);

    if (ws_size >= need) {
        char* ws = (char*)d_ws;
        int* lgn_start = (int*)(ws + o_lgn_start);
        int* bkg_start = (int*)(ws + o_bkg_start);
        unsigned int* lgn_mask = (unsigned int*)(ws + o_lgn_mask);
        unsigned int* bkg_mask = (unsigned int*)(ws + o_bkg_mask);

        int prep_threads = (lgn_C + bkg_C) + (R + 1);
        prep_kernel<<<(prep_threads + 255) / 256, blk, 0, stream>>>(
            lgn_spikes, lgn_C, lgn_mask, bkg_spikes, bkg_C, bkg_mask,
            lgn_rows, nnz_l, lgn_start, bkg_rows, nnz_b, bkg_start, R);

        dim3 grid_main((R + 255) / 256, 4);
        sparse_lut_kernel<<<grid_main, blk, 0, stream>>>(
            lgn_cols, lgn_w, lgn_start,
            bkg_cols, bkg_w, bkg_start,
            lgn_mask, bkg_mask,
            lgn_C, bkg_C, R, out);
    } else {
        dim3 grid_main((R + 255) / 256, 4);
        sparse_fallback_kernel<<<grid_main, blk, 0, stream>>>(
            lgn_rows, lgn_cols, lgn_w, nnz_l,
            bkg_rows, bkg_cols, bkg_w, nnz_b,
            lgn_spikes, bkg_spikes,
            lgn_C, bkg_C, R, out);
    }
}

// Round 9
// 62.765 us; speedup vs baseline: 2.1795x; 1.0603x over previous
//
#include <hip/hip_runtime.h>

#define T_STEPS 128

// ---------------------------------------------------------------------------
// Fused prep: low gids build spike bit-masks in PLANE layout mask[q*C + c]
// (bit t2 of plane q = spike at t = q*32 + t2); high gids build per-row CSR
// starts for both sparse inputs via binary search on the sorted rows.
// ---------------------------------------------------------------------------
__global__ __launch_bounds__(256) void prep_kernel(
    const float* __restrict__ lgn_spikes, int lgn_C, unsigned int* __restrict__ lgn_mask,
    const float* __restrict__ bkg_spikes, int bkg_C, unsigned int* __restrict__ bkg_mask,
    const int* __restrict__ lgn_rows, int nnz_l, int* __restrict__ lgn_start,
    const int* __restrict__ bkg_rows, int nnz_b, int* __restrict__ bkg_start,
    int R)
{
    int gid = blockIdx.x * 256 + threadIdx.x;
    int totC = lgn_C + bkg_C;

    if (gid < totC) {
        const float* sp; unsigned int* mask; int C, cc;
        if (gid < lgn_C) { sp = lgn_spikes; mask = lgn_mask; C = lgn_C; cc = gid; }
        else             { sp = bkg_spikes; mask = bkg_mask; C = bkg_C; cc = gid - lgn_C; }
        unsigned int m0 = 0u, m1 = 0u, m2 = 0u, m3 = 0u;
        #pragma unroll 4
        for (int t = 0; t < 32; ++t) {
            if (sp[(size_t)(t)       * C + cc] != 0.0f) m0 |= (1u << t);
            if (sp[(size_t)(t +  32) * C + cc] != 0.0f) m1 |= (1u << t);
            if (sp[(size_t)(t +  64) * C + cc] != 0.0f) m2 |= (1u << t);
            if (sp[(size_t)(t +  96) * C + cc] != 0.0f) m3 |= (1u << t);
        }
        mask[(size_t)0 * C + cc] = m0;
        mask[(size_t)1 * C + cc] = m1;
        mask[(size_t)2 * C + cc] = m2;
        mask[(size_t)3 * C + cc] = m3;
        return;
    }
    int r = gid - totC;
    if (r <= R) {
        {
            int lo = 0, hi = nnz_l;
            while (lo < hi) { int mid = (lo + hi) >> 1; if (lgn_rows[mid] < r) lo = mid + 1; else hi = mid; }
            lgn_start[r] = lo;
        }
        {
            int lo = 0, hi = nnz_b;
            while (lo < hi) { int mid = (lo + hi) >> 1; if (bkg_rows[mid] < r) lo = mid + 1; else hi = mid; }
            bkg_start[r] = lo;
        }
    }
}

// ---------------------------------------------------------------------------
// Main: thread = (row r, t-quarter q), acc = float[32] in VGPRs.
// Datapath (validated R8): per synapse, mask word -> 8 nibbles ->
// ds_read_b128 of a 16-entry 0/1-float4 LUT + 4 v_fmac each (bit-exact).
// New in R9:
//  (1) 2-deep col/w + 1-deep mask software pipeline: the mask gather for
//      synapse i+1 uses a col loaded a full iteration earlier, covering
//      both hops of the col->mask L2 latency chain.
//  (2) LDS store staging: acc staged into a [16][260] tile (padded: both
//      write and float4-read phases are bank-conflict-free), then stored
//      as float4 -> 1KB contiguous per wave-instr per plane, 2 passes.
// Output written exactly once.
// ---------------------------------------------------------------------------
__global__ __launch_bounds__(256, 6) void sparse_lut_kernel(
    const int* __restrict__ lgn_cols, const float* __restrict__ lgn_w,
    const int* __restrict__ lgn_start,
    const int* __restrict__ bkg_cols, const float* __restrict__ bkg_w,
    const int* __restrict__ bkg_start,
    const unsigned int* __restrict__ lgn_mask,  // [4][lgn_C]
    const unsigned int* __restrict__ bkg_mask,  // [4][bkg_C]
    int lgn_C, int bkg_C, int R,
    float* __restrict__ out)
{
    __shared__ float4 lut[16];
    __shared__ float tile[16 * 260];            // 16 planes x 256 rows, pad->260
    const int tid = threadIdx.x;
    if (tid < 16)
        lut[tid] = make_float4((float)(tid & 1), (float)((tid >> 1) & 1),
                               (float)((tid >> 2) & 1), (float)((tid >> 3) & 1));

    const int r0 = blockIdx.x * 256;
    const int r  = r0 + tid;
    const int q  = blockIdx.y;

    float acc[32];
    #pragma unroll
    for (int t = 0; t < 32; ++t) acc[t] = 0.0f;

    const unsigned int* lm = lgn_mask + (size_t)q * lgn_C;
    const unsigned int* bm = bkg_mask + (size_t)q * bkg_C;

    int l0 = 0, l1 = 0, g0 = 0, g1 = 0;
    if (r < R) {
        l0 = lgn_start[r]; l1 = lgn_start[r + 1];
        g0 = bkg_start[r]; g1 = bkg_start[r + 1];
    }
    __syncthreads();   // lut ready

    #define ACC_MASK(m, wv)                                                  \
        _Pragma("unroll")                                                    \
        for (int nb = 0; nb < 8; ++nb) {                                     \
            float4 s = lut[(m >> (nb * 4)) & 15u];                           \
            acc[nb * 4 + 0] = fmaf(wv, s.x, acc[nb * 4 + 0]);                \
            acc[nb * 4 + 1] = fmaf(wv, s.y, acc[nb * 4 + 1]);                \
            acc[nb * 4 + 2] = fmaf(wv, s.z, acc[nb * 4 + 2]);                \
            acc[nb * 4 + 3] = fmaf(wv, s.w, acc[nb * 4 + 3]);                \
        }

    // 2-deep col/w prefetch, 1-deep mask prefetch
    #define ACC_RANGE(cols_a, w_a, mask_p, I0, I1)                           \
    {                                                                        \
        int i0 = (I0), i1 = (I1);                                            \
        if (i0 < i1) {                                                       \
            float w0 = w_a[i0];                                              \
            int   c1 = 0; float w1 = 0.0f;                                   \
            if (i0 + 1 < i1) { c1 = cols_a[i0 + 1]; w1 = w_a[i0 + 1]; }      \
            unsigned int m0 = mask_p[cols_a[i0]];                            \
            for (int i = i0; i < i1; ++i) {                                  \
                unsigned int m1 = 0u;                                        \
                if (i + 1 < i1) m1 = mask_p[c1];                             \
                int c2 = 0; float w2 = 0.0f;                                 \
                if (i + 2 < i1) { c2 = cols_a[i + 2]; w2 = w_a[i + 2]; }     \
                ACC_MASK(m0, w0)                                             \
                m0 = m1; w0 = w1; c1 = c2; w1 = w2;                          \
            }                                                                \
        }                                                                    \
    }

    ACC_RANGE(lgn_cols, lgn_w, lm, l0, l1)
    ACC_RANGE(bkg_cols, bkg_w, bm, g0, g1)
    #undef ACC_RANGE
    #undef ACC_MASK

    // staged store: 2 passes of 16 planes each
    const int wid  = tid >> 6;
    const int lane = tid & 63;
    #pragma unroll
    for (int pass = 0; pass < 2; ++pass) {
        #pragma unroll
        for (int p = 0; p < 16; ++p)
            tile[p * 260 + tid] = acc[pass * 16 + p];   // banks consecutive
        __syncthreads();
        #pragma unroll
        for (int pp = 0; pp < 4; ++pp) {
            int p  = wid * 4 + pp;
            int rr = r0 + 4 * lane;
            float4 v = *(const float4*)&tile[p * 260 + 4 * lane];
            int t = q * 32 + pass * 16 + p;
            if (rr + 3 < R) {
                *(float4*)&out[(size_t)t * R + rr] = v;
            } else {
                if (rr     < R) out[(size_t)t * R + rr]     = v.x;
                if (rr + 1 < R) out[(size_t)t * R + rr + 1] = v.y;
                if (rr + 2 < R) out[(size_t)t * R + rr + 2] = v.z;
            }
        }
        __syncthreads();
    }
}

// ---------------------------------------------------------------------------
// Fallback (small ws): inline binary search + direct float gathers.
// ---------------------------------------------------------------------------
__global__ __launch_bounds__(256) void sparse_fallback_kernel(
    const int* __restrict__ lgn_rows, const int* __restrict__ lgn_cols,
    const float* __restrict__ lgn_w, int nnz_l,
    const int* __restrict__ bkg_rows, const int* __restrict__ bkg_cols,
    const float* __restrict__ bkg_w, int nnz_b,
    const float* __restrict__ lgn_spikes, const float* __restrict__ bkg_spikes,
    int lgn_C, int bkg_C, int R,
    float* __restrict__ out)
{
    int r = blockIdx.x * 256 + threadIdx.x;
    int q = blockIdx.y;
    if (r >= R) return;

    float acc[32];
    #pragma unroll
    for (int t = 0; t < 32; ++t) acc[t] = 0.0f;

    {
        int lo = 0, hi = nnz_l;
        while (lo < hi) { int mid = (lo + hi) >> 1; if (lgn_rows[mid] < r) lo = mid + 1; else hi = mid; }
        for (int i = lo; i < nnz_l && lgn_rows[i] == r; ++i) {
            float wt = lgn_w[i];
            const float* sp = lgn_spikes + (size_t)(q * 32) * lgn_C + lgn_cols[i];
            #pragma unroll
            for (int t = 0; t < 32; ++t)
                acc[t] = fmaf(wt, sp[(size_t)t * lgn_C], acc[t]);
        }
    }
    {
        int lo = 0, hi = nnz_b;
        while (lo < hi) { int mid = (lo + hi) >> 1; if (bkg_rows[mid] < r) lo = mid + 1; else hi = mid; }
        for (int i = lo; i < nnz_b && bkg_rows[i] == r; ++i) {
            float wt = bkg_w[i];
            const float* sp = bkg_spikes + (size_t)(q * 32) * bkg_C + bkg_cols[i];
            #pragma unroll
            for (int t = 0; t < 32; ++t)
                acc[t] = fmaf(wt, sp[(size_t)t * bkg_C], acc[t]);
        }
    }

    float* op = out + (size_t)(q * 32) * R + r;
    #pragma unroll
    for (int t = 0; t < 32; ++t) op[(size_t)t * R] = acc[t];
}

extern "C" void kernel_launch(void* const* d_in, const int* in_sizes, int n_in,
                              void* d_out, int out_size, void* d_ws, size_t ws_size,
                              hipStream_t stream)
{
    const float* lgn_spikes = (const float*)d_in[0];
    const float* bkg_spikes = (const float*)d_in[1];
    const int*   lgn_rows   = (const int*)d_in[2];
    const int*   lgn_cols   = (const int*)d_in[3];
    const float* lgn_w      = (const float*)d_in[4];
    const int*   bkg_rows   = (const int*)d_in[5];
    const int*   bkg_cols   = (const int*)d_in[6];
    const float* bkg_w      = (const float*)d_in[7];
    float* out = (float*)d_out;

    const int nnz_l = in_sizes[2];
    const int nnz_b = in_sizes[5];
    const int lgn_C = in_sizes[0] / T_STEPS;   // 17400
    const int bkg_C = in_sizes[1] / T_STEPS;   // 100
    const int R     = out_size / T_STEPS;      // 200000

    // ws layout (16B-aligned sections)
    size_t off = 0;
    auto take = [&](size_t bytes) { size_t o = off; off = (off + bytes + 15) & ~(size_t)15; return o; };
    size_t o_lgn_start = take((size_t)(R + 1) * sizeof(int));
    size_t o_bkg_start = take((size_t)(R + 1) * sizeof(int));
    size_t o_lgn_mask  = take((size_t)4 * lgn_C * sizeof(unsigned int));
    size_t o_bkg_mask  = take((size_t)4 * bkg_C * sizeof(unsigned int));
    size_t need = off;

    dim3 blk(256);

    if (ws_size >= need) {
        char* ws = (char*)d_ws;
        int* lgn_start = (int*)(ws + o_lgn_start);
        int* bkg_start = (int*)(ws + o_bkg_start);
        unsigned int* lgn_mask = (unsigned int*)(ws + o_lgn_mask);
        unsigned int* bkg_mask = (unsigned int*)(ws + o_bkg_mask);

        int prep_threads = (lgn_C + bkg_C) + (R + 1);
        prep_kernel<<<(prep_threads + 255) / 256, blk, 0, stream>>>(
            lgn_spikes, lgn_C, lgn_mask, bkg_spikes, bkg_C, bkg_mask,
            lgn_rows, nnz_l, lgn_start, bkg_rows, nnz_b, bkg_start, R);

        dim3 grid_main((R + 255) / 256, 4);
        sparse_lut_kernel<<<grid_main, blk, 0, stream>>>(
            lgn_cols, lgn_w, lgn_start,
            bkg_cols, bkg_w, bkg_start,
            lgn_mask, bkg_mask,
            lgn_C, bkg_C, R, out);
    } else {
        dim3 grid_main((R + 255) / 256, 4);
        sparse_fallback_kernel<<<grid_main, blk, 0, stream>>>(
            lgn_rows, lgn_cols, lgn_w, nnz_l,
            bkg_rows, bkg_cols, bkg_w, nnz_b,
            lgn_spikes, bkg_spikes,
            lgn_C, bkg_C, R, out);
    }
}

// Round 11
// 51.146 us; speedup vs baseline: 2.6746x; 1.2272x over previous
//
#include <hip/hip_runtime.h>

#define T_STEPS 128

// native clang vector for nontemporal 16B stores (HIP float4 is a class type)
typedef float vfloat4 __attribute__((ext_vector_type(4)));

// ---------------------------------------------------------------------------
// Fused prep, three thread segments:
//   [0, totC)                : build spike masks, PAIRED layout mask[q*C+c] =
//                              uint2{bits t=q*64+0..31, bits t=q*64+32..63}
//   [totC, totC+nnz_l)       : lgn CSR starts via adjacent-difference fill
//   [totC+nnz_l, +nnz_b)     : bkg CSR starts likewise
// start[r] = lower_bound(rows, r): thread i writes start[r]=i for all r in
// (rows[i-1], rows[i]]; thread 0 covers [0, rows[0]]; last thread fills tail.
// ---------------------------------------------------------------------------
__global__ __launch_bounds__(256) void prep_kernel(
    const float* __restrict__ lgn_spikes, int lgn_C, uint2* __restrict__ lgn_mask,
    const float* __restrict__ bkg_spikes, int bkg_C, uint2* __restrict__ bkg_mask,
    const int* __restrict__ lgn_rows, int nnz_l, int* __restrict__ lgn_start,
    const int* __restrict__ bkg_rows, int nnz_b, int* __restrict__ bkg_start,
    int R)
{
    int gid = blockIdx.x * 256 + threadIdx.x;
    int totC = lgn_C + bkg_C;

    if (gid < totC) {
        const float* sp; uint2* mask; int C, cc;
        if (gid < lgn_C) { sp = lgn_spikes; mask = lgn_mask; C = lgn_C; cc = gid; }
        else             { sp = bkg_spikes; mask = bkg_mask; C = bkg_C; cc = gid - lgn_C; }
        unsigned int m0 = 0u, m1 = 0u, m2 = 0u, m3 = 0u;
        #pragma unroll 4
        for (int t = 0; t < 32; ++t) {
            if (sp[(size_t)(t)       * C + cc] != 0.0f) m0 |= (1u << t);
            if (sp[(size_t)(t +  32) * C + cc] != 0.0f) m1 |= (1u << t);
            if (sp[(size_t)(t +  64) * C + cc] != 0.0f) m2 |= (1u << t);
            if (sp[(size_t)(t +  96) * C + cc] != 0.0f) m3 |= (1u << t);
        }
        mask[(size_t)0 * C + cc] = make_uint2(m0, m1);   // half 0: t in [0,64)
        mask[(size_t)1 * C + cc] = make_uint2(m2, m3);   // half 1: t in [64,128)
        return;
    }

    int i = gid - totC;
    const int* rows; int nnz; int* start;
    if (i < nnz_l) { rows = lgn_rows; nnz = nnz_l; start = lgn_start; }
    else {
        i -= nnz_l;
        if (i >= nnz_b) return;
        rows = bkg_rows; nnz = nnz_b; start = bkg_start;
    }
    int cur  = rows[i];
    int prev = (i == 0) ? -1 : rows[i - 1];
    for (int rr = prev + 1; rr <= cur; ++rr) start[rr] = i;
    if (i == nnz - 1)
        for (int rr = cur + 1; rr <= R; ++rr) start[rr] = nnz;
}

// ---------------------------------------------------------------------------
// Main: thread = (row r, t-HALF q), acc = float[64] in VGPRs
// (launch_bounds(256,4) -> 128-VGPR budget).
// Per synapse (visited 2x total now, not 4x): 1 col + 1 w load + ONE uint2
// (8B) mask gather; 16 nibbles -> ds_read_b128 16-entry 0/1-float4 LUT +
// 4 v_fmac each (bit-exact). 2-deep col/w + 1-deep mask pipeline covers the
// col->mask chain. Stores staged via LDS tile -> vfloat4 nontemporal stores
// (1KB/wave-instr, bypass L2 since output is never re-read). Output written
// exactly once.
// ---------------------------------------------------------------------------
__global__ __launch_bounds__(256, 4) void sparse_lut_kernel(
    const int* __restrict__ lgn_cols, const float* __restrict__ lgn_w,
    const int* __restrict__ lgn_start,
    const int* __restrict__ bkg_cols, const float* __restrict__ bkg_w,
    const int* __restrict__ bkg_start,
    const uint2* __restrict__ lgn_mask,   // [2][lgn_C]
    const uint2* __restrict__ bkg_mask,   // [2][bkg_C]
    int lgn_C, int bkg_C, int R,
    float* __restrict__ out)
{
    __shared__ float4 lut[16];
    __shared__ float tile[16 * 260];
    const int tid = threadIdx.x;
    if (tid < 16)
        lut[tid] = make_float4((float)(tid & 1), (float)((tid >> 1) & 1),
                               (float)((tid >> 2) & 1), (float)((tid >> 3) & 1));

    const int r0 = blockIdx.x * 256;
    const int r  = r0 + tid;
    const int q  = blockIdx.y;            // t-half: 0 or 1

    float acc[64];
    #pragma unroll
    for (int t = 0; t < 64; ++t) acc[t] = 0.0f;

    const uint2* lm = lgn_mask + (size_t)q * lgn_C;
    const uint2* bm = bkg_mask + (size_t)q * bkg_C;

    int l0 = 0, l1 = 0, g0 = 0, g1 = 0;
    if (r < R) {
        l0 = lgn_start[r]; l1 = lgn_start[r + 1];
        g0 = bkg_start[r]; g1 = bkg_start[r + 1];
    }
    __syncthreads();   // lut ready

    #define ACC_WORD(mw, base, wv)                                           \
        _Pragma("unroll")                                                    \
        for (int nb = 0; nb < 8; ++nb) {                                     \
            float4 s = lut[((mw) >> (nb * 4)) & 15u];                        \
            acc[(base) + nb * 4 + 0] = fmaf(wv, s.x, acc[(base) + nb * 4 + 0]); \
            acc[(base) + nb * 4 + 1] = fmaf(wv, s.y, acc[(base) + nb * 4 + 1]); \
            acc[(base) + nb * 4 + 2] = fmaf(wv, s.z, acc[(base) + nb * 4 + 2]); \
            acc[(base) + nb * 4 + 3] = fmaf(wv, s.w, acc[(base) + nb * 4 + 3]); \
        }

    // 2-deep col/w prefetch, 1-deep mask prefetch
    #define ACC_RANGE(cols_a, w_a, mask_p, I0, I1)                           \
    {                                                                        \
        int i0 = (I0), i1 = (I1);                                            \
        if (i0 < i1) {                                                       \
            float w0 = w_a[i0];                                              \
            int   c1 = 0; float w1 = 0.0f;                                   \
            if (i0 + 1 < i1) { c1 = cols_a[i0 + 1]; w1 = w_a[i0 + 1]; }      \
            uint2 m0 = mask_p[cols_a[i0]];                                   \
            for (int i = i0; i < i1; ++i) {                                  \
                uint2 m1v = make_uint2(0u, 0u);                              \
                if (i + 1 < i1) m1v = mask_p[c1];                            \
                int c2 = 0; float w2 = 0.0f;                                 \
                if (i + 2 < i1) { c2 = cols_a[i + 2]; w2 = w_a[i + 2]; }     \
                ACC_WORD(m0.x, 0,  w0)                                       \
                ACC_WORD(m0.y, 32, w0)                                       \
                m0 = m1v; w0 = w1; c1 = c2; w1 = w2;                         \
            }                                                                \
        }                                                                    \
    }

    ACC_RANGE(lgn_cols, lgn_w, lm, l0, l1)
    ACC_RANGE(bkg_cols, bkg_w, bm, g0, g1)
    #undef ACC_RANGE
    #undef ACC_WORD

    // staged store: 4 passes of 16 planes; vfloat4 nontemporal stores
    const int wid  = tid >> 6;
    const int lane = tid & 63;
    #pragma unroll
    for (int pass = 0; pass < 4; ++pass) {
        #pragma unroll
        for (int p = 0; p < 16; ++p)
            tile[p * 260 + tid] = acc[pass * 16 + p];
        __syncthreads();
        #pragma unroll
        for (int pp = 0; pp < 4; ++pp) {
            int p  = wid * 4 + pp;
            int rr = r0 + 4 * lane;
            vfloat4 v = *(const vfloat4*)&tile[p * 260 + 4 * lane];
            int t = q * 64 + pass * 16 + p;
            float* dst = &out[(size_t)t * R + rr];
            if (rr + 3 < R) {
                __builtin_nontemporal_store(v, (vfloat4*)dst);
            } else {
                if (rr     < R) __builtin_nontemporal_store(v.x, dst);
                if (rr + 1 < R) __builtin_nontemporal_store(v.y, dst + 1);
                if (rr + 2 < R) __builtin_nontemporal_store(v.z, dst + 2);
            }
        }
        __syncthreads();
    }
}

// ---------------------------------------------------------------------------
// Fallback (small ws): inline binary search + direct float gathers.
// ---------------------------------------------------------------------------
__global__ __launch_bounds__(256) void sparse_fallback_kernel(
    const int* __restrict__ lgn_rows, const int* __restrict__ lgn_cols,
    const float* __restrict__ lgn_w, int nnz_l,
    const int* __restrict__ bkg_rows, const int* __restrict__ bkg_cols,
    const float* __restrict__ bkg_w, int nnz_b,
    const float* __restrict__ lgn_spikes, const float* __restrict__ bkg_spikes,
    int lgn_C, int bkg_C, int R,
    float* __restrict__ out)
{
    int r = blockIdx.x * 256 + threadIdx.x;
    int q = blockIdx.y;
    if (r >= R) return;

    float acc[32];
    #pragma unroll
    for (int t = 0; t < 32; ++t) acc[t] = 0.0f;

    {
        int lo = 0, hi = nnz_l;
        while (lo < hi) { int mid = (lo + hi) >> 1; if (lgn_rows[mid] < r) lo = mid + 1; else hi = mid; }
        for (int i = lo; i < nnz_l && lgn_rows[i] == r; ++i) {
            float wt = lgn_w[i];
            const float* sp = lgn_spikes + (size_t)(q * 32) * lgn_C + lgn_cols[i];
            #pragma unroll
            for (int t = 0; t < 32; ++t)
                acc[t] = fmaf(wt, sp[(size_t)t * lgn_C], acc[t]);
        }
    }
    {
        int lo = 0, hi = nnz_b;
        while (lo < hi) { int mid = (lo + hi) >> 1; if (bkg_rows[mid] < r) lo = mid + 1; else hi = mid; }
        for (int i = lo; i < nnz_b && bkg_rows[i] == r; ++i) {
            float wt = bkg_w[i];
            const float* sp = bkg_spikes + (size_t)(q * 32) * bkg_C + bkg_cols[i];
            #pragma unroll
            for (int t = 0; t < 32; ++t)
                acc[t] = fmaf(wt, sp[(size_t)t * bkg_C], acc[t]);
        }
    }

    float* op = out + (size_t)(q * 32) * R + r;
    #pragma unroll
    for (int t = 0; t < 32; ++t) op[(size_t)t * R] = acc[t];
}

extern "C" void kernel_launch(void* const* d_in, const int* in_sizes, int n_in,
                              void* d_out, int out_size, void* d_ws, size_t ws_size,
                              hipStream_t stream)
{
    const float* lgn_spikes = (const float*)d_in[0];
    const float* bkg_spikes = (const float*)d_in[1];
    const int*   lgn_rows   = (const int*)d_in[2];
    const int*   lgn_cols   = (const int*)d_in[3];
    const float* lgn_w      = (const float*)d_in[4];
    const int*   bkg_rows   = (const int*)d_in[5];
    const int*   bkg_cols   = (const int*)d_in[6];
    const float* bkg_w      = (const float*)d_in[7];
    float* out = (float*)d_out;

    const int nnz_l = in_sizes[2];
    const int nnz_b = in_sizes[5];
    const int lgn_C = in_sizes[0] / T_STEPS;   // 17400
    const int bkg_C = in_sizes[1] / T_STEPS;   // 100
    const int R     = out_size / T_STEPS;      // 200000

    // ws layout (16B-aligned sections)
    size_t off = 0;
    auto take = [&](size_t bytes) { size_t o = off; off = (off + bytes + 15) & ~(size_t)15; return o; };
    size_t o_lgn_start = take((size_t)(R + 1) * sizeof(int));
    size_t o_bkg_start = take((size_t)(R + 1) * sizeof(int));
    size_t o_lgn_mask  = take((size_t)2 * lgn_C * sizeof(uint2));
    size_t o_bkg_mask  = take((size_t)2 * bkg_C * sizeof(uint2));
    size_t need = off;

    dim3 blk(256);

    if (ws_size >= need) {
        char* ws = (char*)d_ws;
        int* lgn_start = (int*)(ws + o_lgn_start);
        int* bkg_start = (int*)(ws + o_bkg_start);
        uint2* lgn_mask = (uint2*)(ws + o_lgn_mask);
        uint2* bkg_mask = (uint2*)(ws + o_bkg_mask);

        int prep_threads = (lgn_C + bkg_C) + nnz_l + nnz_b;
        prep_kernel<<<(prep_threads + 255) / 256, blk, 0, stream>>>(
            lgn_spikes, lgn_C, lgn_mask, bkg_spikes, bkg_C, bkg_mask,
            lgn_rows, nnz_l, lgn_start, bkg_rows, nnz_b, bkg_start, R);

        dim3 grid_main((R + 255) / 256, 2);
        sparse_lut_kernel<<<grid_main, blk, 0, stream>>>(
            lgn_cols, lgn_w, lgn_start,
            bkg_cols, bkg_w, bkg_start,
            lgn_mask, bkg_mask,
            lgn_C, bkg_C, R, out);
    } else {
        dim3 grid_main((R + 255) / 256, 4);
        sparse_fallback_kernel<<<grid_main, blk, 0, stream>>>(
            lgn_rows, lgn_cols, lgn_w, nnz_l,
            bkg_rows, bkg_cols, bkg_w, nnz_b,
            lgn_spikes, bkg_spikes,
            lgn_C, bkg_C, R, out);
    }
}